// Round 3
// baseline (193.787 us; speedup 1.0000x reference)
//
#include <hip/hip_runtime.h>
#include <math.h>

#define MIN_T    0.01f
#define MAX_T    0.5f
#define LESION_T 0.3f

constexpr int NB       = 16;
constexpr int DIM      = 128;
constexpr int PLANE_F4 = DIM * DIM / 4;        // 4096 float4 per plane
constexpr int VOX      = DIM * DIM * DIM;      // 2,097,152
constexpr int THREADS  = 256;
constexpr int HWBLKS   = PLANE_F4 / THREADS;   // 16 row-slabs (8 rows each)
constexpr int DSEGS    = 8;                    // d-axis segments
constexpr int DPS      = DIM / DSEGS;          // 16 planes per segment
constexpr int NACC     = 8;

// Accumulator layout per batch (doubles):
// 0: cnt(>MIN_T)  1: cnt(>MAX_T)  2: sum|d-diff|  3: sum|h-diff|
// 4: sum|w-diff|  5: sum s*mask   6: sum s^2*mask 7: cnt(>LESION_T)
__global__ __launch_bounds__(THREADS, 8)   // 8 waves/EU -> cap VGPRs for full occupancy
void partial_kernel(const float* __restrict__ pred, double* __restrict__ acc)
{
    const int seg   = blockIdx.x;
    const int hwblk = blockIdx.y;
    const int b     = blockIdx.z;
    const int tid   = (int)threadIdx.x;

    const float4* __restrict__ s4 =
        reinterpret_cast<const float4*>(pred + (size_t)b * VOX);

    // thread owns float4 at (h = hwblk*8 + tid/32, w4 = tid%32) on every plane
    const int  h    = hwblk * 8 + (tid >> 5);
    const bool do_h = (h < DIM - 1);            // h-pair (h,h+1) exists
    const bool do_w = ((tid & 31) != 31);       // w-cross pair exists (not row end)

    const int d0    = seg * DPS;
    // pairs (d,d+1) for d in [d0, d0+npair); stats planes d0..d0+DPS-1
    const int npair = (seg == DSEGS - 1) ? (DPS - 1) : DPS;
    const int last  = d0 + npair;               // highest plane index loaded

    float cnt_min = 0.f, cnt_max = 0.f, sum_d = 0.f, sum_h = 0.f,
          sum_w = 0.f, sm = 0.f, sm2 = 0.f, les = 0.f;

    auto process = [&](const float4& v, const float4& vh) {
        const float xs[4] = { v.x, v.y, v.z, v.w };
        #pragma unroll
        for (int j = 0; j < 4; ++j) {
            const float x    = xs[j];
            const bool  gmin = (x > MIN_T);
            const float xm   = gmin ? x : 0.0f;
            cnt_min += gmin ? 1.0f : 0.0f;
            sm      += xm;
            sm2      = fmaf(xm, x, sm2);
            cnt_max += (x > MAX_T)    ? 1.0f : 0.0f;
            les     += (x > LESION_T) ? 1.0f : 0.0f;
        }
        sum_w += fabsf(v.y - v.x) + fabsf(v.z - v.y) + fabsf(v.w - v.z);
        const float nx = __shfl_down(v.x, 1, 64);   // next float4's .x, same row
        if (do_w) sum_w += fabsf(nx - v.w);
        if (do_h) sum_h += fabsf(vh.x - v.x) + fabsf(vh.y - v.y)
                         + fabsf(vh.z - v.z) + fabsf(vh.w - v.w);
    };

    const float4 z4 = { 0.f, 0.f, 0.f, 0.f };
    const size_t off = (size_t)hwblk * THREADS + tid;
    size_t base = (size_t)d0 * PLANE_F4 + off;
    const size_t lastbase = (size_t)last * PLANE_F4 + off;

    // 2-deep software pipeline over planes
    float4 v0 = s4[base];
    float4 h0 = do_h ? s4[base + 32] : z4;
    float4 v1 = s4[base + PLANE_F4];
    float4 h1 = do_h ? s4[base + PLANE_F4 + 32] : z4;
    size_t pbase = base + 2 * (size_t)PLANE_F4;

    for (int d = d0; d < d0 + npair; ++d) {
        const size_t pf = (pbase < lastbase) ? pbase : lastbase;  // clamp tail
        const float4 v2 = s4[pf];
        const float4 h2 = do_h ? s4[pf + 32] : z4;
        process(v0, h0);
        sum_d += fabsf(v1.x - v0.x) + fabsf(v1.y - v0.y)
               + fabsf(v1.z - v0.z) + fabsf(v1.w - v0.w);
        v0 = v1; h0 = h1; v1 = v2; h1 = h2;
        pbase += PLANE_F4;
    }
    if (seg == DSEGS - 1)     // plane 127 stats (no outgoing d-pair)
        process(v0, h0);

    // wave (64-lane) shuffle reduction, then LDS across 4 waves
    float vals[NACC] = { cnt_min, cnt_max, sum_d, sum_h, sum_w, sm, sm2, les };
    #pragma unroll
    for (int vi = 0; vi < NACC; ++vi) {
        float x = vals[vi];
        #pragma unroll
        for (int offs = 32; offs > 0; offs >>= 1)
            x += __shfl_down(x, offs, 64);
        vals[vi] = x;
    }

    __shared__ float smem[4][NACC];
    const int wave = tid >> 6;
    const int lane = tid & 63;
    if (lane == 0) {
        #pragma unroll
        for (int vi = 0; vi < NACC; ++vi) smem[wave][vi] = vals[vi];
    }
    __syncthreads();
    if (tid < NACC) {
        const float t = smem[0][tid] + smem[1][tid] +
                        smem[2][tid] + smem[3][tid];
        atomicAdd(&acc[(size_t)b * NACC + tid], (double)t);
    }
}

__global__ __launch_bounds__(64)
void finalize_kernel(const double* __restrict__ acc, float* __restrict__ out)
{
    float l = 0.0f;
    if (threadIdx.x < NB) {
        const double* a = acc + (size_t)threadIdx.x * NACC;
        const double cnt    = a[0];
        const double cntmax = a[1];
        const double sd     = a[2];
        const double sh     = a[3];
        const double sw     = a[4];
        const double sm     = a[5];
        const double sm2    = a[6];
        const double les    = a[7];

        const double inv_vox = 1.0 / (double)VOX;
        const double act  = cnt    * inv_vox;
        const double high = cntmax * inv_vox;

        double loss = fmax(0.005 - act, 0.0) * 15.0      // W_MIN
                    + fmax(high - 0.03, 0.0) * 5.0;      // W_MAX

        const double grad_den = 127.0 * 128.0 * 128.0;   // diff-array size
        const double avg_grad = (sd + sh + sw) / (3.0 * grad_den);
        if (les > 0.5)
            loss += fmin(avg_grad, 1.0) * 5.0;           // W_CONT

        const double cnt_safe = fmax(cnt, 1.0);
        const double m  = sm / cnt_safe;
        double sq = sm2 - 2.0 * m * sm + m * m * cnt;
        if (sq < 0.0) sq = 0.0;

        const bool gate = (act > 0.001) && (cnt > 1.0);
        if (gate) {
            const double var     = sq / fmax(cnt - 1.0, 1.0);
            const double rel_std = sqrt(var) / (m + 1e-6);
            loss += exp(-5.0 * rel_std) * 7.0;           // W_SIZE
        }
        l = (float)loss;
    }
    #pragma unroll
    for (int offs = 32; offs > 0; offs >>= 1)
        l += __shfl_down(l, offs, 64);
    if (threadIdx.x == 0)
        out[0] = l / (float)NB;
}

extern "C" void kernel_launch(void* const* d_in, const int* in_sizes, int n_in,
                              void* d_out, int out_size, void* d_ws, size_t ws_size,
                              hipStream_t stream)
{
    const float* pred = (const float*)d_in[0];
    float* out        = (float*)d_out;
    double* acc       = (double*)d_ws;

    hipMemsetAsync(d_ws, 0, (size_t)NB * NACC * sizeof(double), stream);

    dim3 grid(DSEGS, HWBLKS, NB);
    partial_kernel<<<grid, THREADS, 0, stream>>>(pred, acc);
    finalize_kernel<<<1, 64, 0, stream>>>(acc, out);
}